// Round 5
// baseline (488.060 us; speedup 1.0000x reference)
//
#include <hip/hip_runtime.h>

typedef unsigned short u16;
typedef short bf16x8 __attribute__((ext_vector_type(8)));
typedef float f32x4 __attribute__((ext_vector_type(4)));

__device__ __forceinline__ u16 f2bf(float f) {
  union { float f; unsigned u; } v; v.f = f;
  unsigned r = v.u + 0x7fffu + ((v.u >> 16) & 1u);
  return (u16)(r >> 16);
}

#define MFMA_B16(a, b, c) __builtin_amdgcn_mfma_f32_16x16x32_bf16((a), (b), (c), 0, 0, 0)

// Stage ROWS x 64-u16 tile global->LDS, 512-thread block (8 waves).
// LDS holds swizzled layout LDS[row][slot] = global[row][slot ^ (row&7)]
// via pre-swizzled per-lane global source + linear LDS dest (rule 21/m173).
template<int ROWS>
__device__ __forceinline__ void stage8(const u16* __restrict__ gbase, int ldg,
                                       u16* lds, int tid) {
  const int wave = tid >> 6, lane = tid & 63;
  const int r8 = lane >> 3, slot = lane & 7;
#pragma unroll
  for (int j = 0; j < ROWS / 64; ++j) {
    const int chunk = wave + j * 8;
    const int row = chunk * 8 + r8;
    const u16* g = gbase + (size_t)row * ldg + ((slot ^ (row & 7)) << 3);
    __builtin_amdgcn_global_load_lds(
        (const __attribute__((address_space(1))) void*)g,
        (__attribute__((address_space(3))) void*)(lds + chunk * 512),
        16, 0, 0);
  }
}

// 256xBN tile GEMM core, 8 waves as 2(M)x4(N), wave tile 128 x BN/4.
// acc[8][FN], FN = BN/64. A: rows=M (ld=ldg), B: rows=N (ld=ldg), NT product.
template<int BN, int FN>
__device__ __forceinline__ void gemm_core(const u16* __restrict__ A,
                                          const u16* __restrict__ B,
                                          int ldg, int kBeg, int kEnd,
                                          u16* As, u16* Bs,
                                          f32x4 (&acc)[8][FN], int tid) {
  const int wave = tid >> 6, lane = tid & 63;
  const int wm = wave >> 2, wn = wave & 3;
  const int lrow = lane & 15, lk = lane >> 4;
  for (int k0 = kBeg; k0 < kEnd; k0 += 64) {
    __syncthreads();
    stage8<256>(A + k0, ldg, As, tid);
    stage8<BN>(B + k0, ldg, Bs, tid);
    __syncthreads();
#pragma unroll
    for (int ks = 0; ks < 2; ++ks) {
      bf16x8 b[FN];
#pragma unroll
      for (int fn = 0; fn < FN; ++fn) {
        int r = wn * (BN / 4) + fn * 16 + lrow;
        b[fn] = *(const bf16x8*)(Bs + r * 64 + (((ks * 4 + lk) ^ (r & 7)) * 8));
      }
#pragma unroll
      for (int fm = 0; fm < 8; ++fm) {
        int r = wm * 128 + fm * 16 + lrow;
        bf16x8 a = *(const bf16x8*)(As + r * 64 + (((ks * 4 + lk) ^ (r & 7)) * 8));
#pragma unroll
        for (int fn = 0; fn < FN; ++fn)
          acc[fm][fn] = MFMA_B16(a, b[fn], acc[fm][fn]);
      }
    }
  }
}

// ---------------- K0: fp32 -> bf16 conversion (x and the 3 weights) ----------------
__global__ void __launch_bounds__(256) convert_kernel(
    const float* __restrict__ x, const float* __restrict__ Wq,
    const float* __restrict__ Wk, const float* __restrict__ Wv,
    u16* __restrict__ xb, u16* __restrict__ Wb) {
  int i = blockIdx.x * 256 + threadIdx.x;
  const int NX4 = 2097152;
  if (i < NX4) {
    const float4 v = ((const float4*)x)[i];
    ushort4 o; o.x = f2bf(v.x); o.y = f2bf(v.y); o.z = f2bf(v.z); o.w = f2bf(v.w);
    ((ushort4*)xb)[i] = o;
  } else {
    int j4 = i - NX4;
    int j = j4 * 4;
    const float* W = (j < 65536) ? Wq : ((j < 131072) ? Wk : Wv);
    const float4 v = *(const float4*)(W + (j & 65535));
    ushort4 o; o.x = f2bf(v.x); o.y = f2bf(v.y); o.z = f2bf(v.z); o.w = f2bf(v.w);
    ((ushort4*)Wb)[j4] = o;
  }
}

// ---------------- K1: linear (x @ W.T + b), 256x256 tiles, permute-scatter epilogue ----------------
__global__ void __launch_bounds__(512) linear_kernel(
    const u16* __restrict__ xb, const u16* __restrict__ Wb,
    const float* __restrict__ bq, const float* __restrict__ bk, const float* __restrict__ bv,
    float* __restrict__ q_lin, float* __restrict__ k_lin, u16* __restrict__ vT) {
  __shared__ __align__(16) u16 As[256 * 64];
  __shared__ __align__(16) u16 Bs[256 * 64];
  const int tid = threadIdx.x;
  const int m0 = blockIdx.x * 256, n0 = blockIdx.y * 256;
  const int wave = tid >> 6, lane = tid & 63;
  const int wm = wave >> 2, wn = wave & 3;
  const int lrow = lane & 15, lk = lane >> 4;
  const f32x4 fzero = {0.f, 0.f, 0.f, 0.f};
  f32x4 acc[8][4];
  for (int a = 0; a < 8; ++a) for (int b = 0; b < 4; ++b) acc[a][b] = fzero;

  gemm_core<256, 4>(xb + (size_t)m0 * 256, Wb + (size_t)n0 * 256, 256, 0, 256,
                    As, Bs, acc, tid);

  const int w = n0 >> 8;  // whole tile is one of q/k/v
  for (int fm = 0; fm < 8; ++fm)
    for (int fn = 0; fn < 4; ++fn)
      for (int r = 0; r < 4; ++r) {
        int grow = wm * 128 + fm * 16 + lk * 4 + r;
        int gcol = wn * 64 + fn * 16 + lrow;
        int m = m0 + grow, j = n0 + gcol;
        int rx = m >> 11, c = m & 2047;
        int jj = j & 255, h = jj >> 5, e = jj & 31;
        int h2 = c >> 8, c2 = ((c & 255) << 3) + h, d2 = (rx << 5) + e;
        float bias = (w == 0) ? bq[jj] : ((w == 1) ? bk[jj] : bv[jj]);
        float val = acc[fm][fn][r] + bias;
        size_t qk_off = ((size_t)((h2 << 11) + c2) << 9) + d2;
        if (w == 0)      q_lin[qk_off] = val;
        else if (w == 1) k_lin[qk_off] = val;
        else             vT[(((size_t)(h2 << 9) + d2) << 11) + c2] = f2bf(val);
      }
}

// ---------------- K2: softmax over d (512) per (h,n) row; fold *sqrt(512) ----------------
__global__ void __launch_bounds__(256) softmax_q_kernel(
    const float* __restrict__ q_lin, u16* __restrict__ qb) {
  const int row = blockIdx.x, tid = threadIdx.x;
  const int wave = tid >> 6, lane = tid & 63;
  const float* src = q_lin + ((size_t)row << 9);
  float v0 = src[tid], v1 = src[tid + 256];
  float m = fmaxf(v0, v1);
  for (int o = 32; o; o >>= 1) m = fmaxf(m, __shfl_xor(m, o));
  __shared__ float red[8];
  if (lane == 0) red[wave] = m;
  __syncthreads();
  m = fmaxf(fmaxf(red[0], red[1]), fmaxf(red[2], red[3]));
  float e0 = expf(v0 - m), e1 = expf(v1 - m);
  float s = e0 + e1;
  for (int o = 32; o; o >>= 1) s += __shfl_xor(s, o);
  if (lane == 0) red[4 + wave] = s;
  __syncthreads();
  s = red[4] + red[5] + red[6] + red[7];
  float sc = 22.627416997969522f / s;
  u16* dst = qb + ((size_t)row << 9);
  dst[tid] = f2bf(e0 * sc);
  dst[tid + 256] = f2bf(e1 * sc);
}

// ---------------- K3a: per-chunk partial (max, sum-exp) over n for each (h,d) column ----------------
__global__ void __launch_bounds__(256) softmax_k_part_kernel(
    const float* __restrict__ k_lin, float2* __restrict__ partials) {
  const int tid = threadIdx.x;
  const int dl = tid & 63, ng = tid >> 6;
  const int dt = blockIdx.x, h = blockIdx.y, nch = blockIdx.z;
  const int d = dt * 64 + dl;
  const float* base = k_lin + ((size_t)h << 20) + ((size_t)(nch * 128 + ng * 32) << 9) + d;
  float v[32];
  #pragma unroll
  for (int i = 0; i < 32; ++i) v[i] = base[(size_t)i << 9];
  float m = v[0];
  #pragma unroll
  for (int i = 1; i < 32; ++i) m = fmaxf(m, v[i]);
  __shared__ float2 red[4][64];
  red[ng][dl].x = m;
  __syncthreads();
  float M = fmaxf(fmaxf(red[0][dl].x, red[1][dl].x), fmaxf(red[2][dl].x, red[3][dl].x));
  float s = 0.f;
  #pragma unroll
  for (int i = 0; i < 32; ++i) s += __expf(v[i] - M);
  red[ng][dl].y = s;
  __syncthreads();
  if (ng == 0) {
    float S = red[0][dl].y + red[1][dl].y + red[2][dl].y + red[3][dl].y;
    partials[(((h * 8 + dt) * 16 + nch) << 6) + dl] = make_float2(M, S);
  }
}

// ---------------- K3c: combine partials, normalize, write kb (coalesced) + kT (LDS transpose) ----------------
__global__ void __launch_bounds__(256) softmax_k_norm_kernel(
    const float* __restrict__ k_lin, const float2* __restrict__ partials,
    u16* __restrict__ kb, u16* __restrict__ kT) {
  __shared__ __align__(16) u16 Ts[64 * 128];
  const int tid = threadIdx.x;
  const int dl = tid & 63, ng = tid >> 6;
  const int dt = blockIdx.x, h = blockIdx.y, nch = blockIdx.z;
  const int d0 = dt * 64, n0 = nch * 128;
  const float2* pb = partials + (((h * 8 + dt) * 16) << 6) + dl;
  float2 pj[16];
  float M = -3.0e38f;
  #pragma unroll
  for (int j = 0; j < 16; ++j) { pj[j] = pb[j << 6]; M = fmaxf(M, pj[j].x); }
  float S = 0.f;
  #pragma unroll
  for (int j = 0; j < 16; ++j) S += pj[j].y * __expf(pj[j].x - M);
  float inv = 1.0f / S;
  const float* src = k_lin + ((size_t)h << 20) + ((size_t)(n0 + ng * 32) << 9) + d0 + dl;
  u16* kbp = kb + ((size_t)h << 20) + ((size_t)(n0 + ng * 32) << 9) + d0 + dl;
  bf16x8 pk[4];
  #pragma unroll
  for (int i = 0; i < 32; ++i) {
    float e = __expf(src[(size_t)i << 9] - M) * inv;
    u16 b = f2bf(e);
    kbp[(size_t)i << 9] = b;
    pk[i >> 3][i & 7] = (short)b;
  }
  #pragma unroll
  for (int j = 0; j < 4; ++j) {
    int nl8 = ng * 4 + j;
    *(bf16x8*)(Ts + dl * 128 + (((nl8 * 8) ^ ((dl & 7) << 3)))) = pk[j];
  }
  __syncthreads();
  const int rd = tid >> 2;
  u16* kTp = kT + ((size_t)h << 20) + ((size_t)(d0 + rd) << 11) + n0;
  #pragma unroll
  for (int j = 0; j < 4; ++j) {
    int g = (tid & 3) + j * 4;
    bf16x8 vv = *(const bf16x8*)(Ts + rd * 128 + (((g * 8) ^ ((rd & 7) << 3))));
    *(bf16x8*)(kTp + g * 8) = vv;
  }
}

// ---------------- K4: attn[h,n,m] = sum_d qb[h,n,d]*kb[h,m,d]  (NT, 256x256, K=512) ----------------
__global__ void __launch_bounds__(512) attn_kernel(
    const u16* __restrict__ qb, const u16* __restrict__ kb, float* __restrict__ attn) {
  __shared__ __align__(16) u16 As[256 * 64];
  __shared__ __align__(16) u16 Bs[256 * 64];
  const int tid = threadIdx.x, h = blockIdx.z;
  const int n0 = blockIdx.x * 256, mm0 = blockIdx.y * 256;
  const int wave = tid >> 6, lane = tid & 63;
  const int wm = wave >> 2, wn = wave & 3;
  const int lrow = lane & 15, lk = lane >> 4;
  const f32x4 fzero = {0.f, 0.f, 0.f, 0.f};
  f32x4 acc[8][4];
  for (int a = 0; a < 8; ++a) for (int b = 0; b < 4; ++b) acc[a][b] = fzero;

  gemm_core<256, 4>(qb + ((size_t)h << 20) + (size_t)n0 * 512,
                    kb + ((size_t)h << 20) + (size_t)mm0 * 512,
                    512, 0, 512, As, Bs, acc, tid);

  float* dst = attn + ((size_t)h << 22);
  for (int fm = 0; fm < 8; ++fm)
    for (int fn = 0; fn < 4; ++fn)
      for (int r = 0; r < 4; ++r) {
        int row = n0 + wm * 128 + fm * 16 + lk * 4 + r;
        int col = mm0 + wn * 64 + fn * 16 + lrow;
        dst[((size_t)row << 11) + col] = acc[fm][fn][r];
      }
}

// ---------------- K5: ctx partials (split-K=4): part[s][h][e][d] = sum_{n in slice} vT*kT ----------------
__global__ void __launch_bounds__(512) ctx_kernel(
    const u16* __restrict__ vT, const u16* __restrict__ kT, float* __restrict__ part) {
  __shared__ __align__(16) u16 As[256 * 64];
  __shared__ __align__(16) u16 Bs[256 * 64];
  const int tid = threadIdx.x;
  const int h = blockIdx.z >> 2, s = blockIdx.z & 3;
  const int e0 = blockIdx.x * 256, d0 = blockIdx.y * 256;
  const int wave = tid >> 6, lane = tid & 63;
  const int wm = wave >> 2, wn = wave & 3;
  const int lrow = lane & 15, lk = lane >> 4;
  const f32x4 fzero = {0.f, 0.f, 0.f, 0.f};
  f32x4 acc[8][4];
  for (int a = 0; a < 8; ++a) for (int b = 0; b < 4; ++b) acc[a][b] = fzero;

  gemm_core<256, 4>(vT + ((size_t)h << 20) + (size_t)e0 * 2048,
                    kT + ((size_t)h << 20) + (size_t)d0 * 2048,
                    2048, s * 512, s * 512 + 512, As, Bs, acc, tid);

  float* dst = part + ((size_t)(s * 8 + h) << 18);
  for (int fm = 0; fm < 8; ++fm)
    for (int fn = 0; fn < 4; ++fn)
      for (int r = 0; r < 4; ++r) {
        int erow = e0 + wm * 128 + fm * 16 + lk * 4 + r;
        int dcol = d0 + wn * 64 + fn * 16 + lrow;
        dst[((size_t)erow << 9) + dcol] = acc[fm][fn][r];
      }
}

// ---------------- K5b: reduce the 4 split-K partials -> ctxT bf16 ----------------
__global__ void __launch_bounds__(256) ctx_reduce_kernel(
    const float* __restrict__ part, u16* __restrict__ ctxT) {
  int i = blockIdx.x * 256 + threadIdx.x;       // float4 index, 524288 total
  const float4* p = (const float4*)part;
  float4 s0 = p[i], s1 = p[i + (1 << 19)], s2 = p[i + (2 << 19)], s3 = p[i + 3 * (1 << 19)];
  ushort4 o;
  o.x = f2bf(s0.x + s1.x + s2.x + s3.x);
  o.y = f2bf(s0.y + s1.y + s2.y + s3.y);
  o.z = f2bf(s0.z + s1.z + s2.z + s3.z);
  o.w = f2bf(s0.w + s1.w + s2.w + s3.w);
  ((ushort4*)ctxT)[i] = o;
}

// ---------------- K6: out[h,n,e] = sum_d qb*ctxT (NT, 256x128, K=512) + inverse permute ----------------
__global__ void __launch_bounds__(512) out_kernel(
    const u16* __restrict__ qb, const u16* __restrict__ ctxT, float* __restrict__ out) {
  __shared__ __align__(16) u16 As[256 * 64];
  __shared__ __align__(16) u16 Bs[128 * 64];
  const int tid = threadIdx.x, h = blockIdx.z;
  const int n0 = blockIdx.x * 256, e0 = blockIdx.y * 128;
  const int wave = tid >> 6, lane = tid & 63;
  const int wm = wave >> 2, wn = wave & 3;
  const int lrow = lane & 15, lk = lane >> 4;
  const f32x4 fzero = {0.f, 0.f, 0.f, 0.f};
  f32x4 acc[8][2];
  for (int a = 0; a < 8; ++a) for (int b = 0; b < 2; ++b) acc[a][b] = fzero;

  gemm_core<128, 2>(qb + ((size_t)h << 20) + (size_t)n0 * 512,
                    ctxT + ((size_t)h << 18) + (size_t)e0 * 512,
                    512, 0, 512, As, Bs, acc, tid);

  for (int fm = 0; fm < 8; ++fm)
    for (int fn = 0; fn < 2; ++fn)
      for (int r = 0; r < 4; ++r) {
        int n = n0 + wm * 128 + fm * 16 + lk * 4 + r;
        int e = e0 + wn * 32 + fn * 16 + lrow;
        size_t dstIdx = ((size_t)(((e >> 5) << 11) + n) << 8) + (h << 5) + (e & 31);
        out[dstIdx] = acc[fm][fn][r];
      }
}

extern "C" void kernel_launch(void* const* d_in, const int* in_sizes, int n_in,
                              void* d_out, int out_size, void* d_ws, size_t ws_size,
                              hipStream_t stream) {
  const float* x  = (const float*)d_in[0];
  const float* Wq = (const float*)d_in[1];
  const float* bq = (const float*)d_in[2];
  const float* Wk = (const float*)d_in[3];
  const float* bk = (const float*)d_in[4];
  const float* Wv = (const float*)d_in[5];
  const float* bv = (const float*)d_in[6];
  float* out  = (float*)d_out;
  float* attn = out + 8388608;

  char* ws = (char*)d_ws;
  u16*   xb    = (u16*)(ws);                      // 16,777,216 B
  u16*   Wb    = (u16*)(ws + 16777216);           //    393,216 B
  float* q_lin = (float*)(ws + 17170432);         // 33,554,432 B
  float* k_lin = (float*)(ws + 50724864);         // 33,554,432 B
  u16*   vT    = (u16*)(ws + 84279296);           // 16,777,216 B
  u16*   qb    = (u16*)(ws);                      // over xb   (dead after K1)
  u16*   kb    = (u16*)(ws + 17170432);           // over q_lin (dead after K2)
  u16*   kT    = (u16*)(ws + 33947648);
  u16*   ctxT  = (u16*)(ws + 50724864);           // over k_lin (dead after K3)
  float* ctx_part = (float*)(ws + 134217728);     // 33,554,432 B split-K partials
  float2* partials = (float2*)(attn + 33554432 - 131072);

  convert_kernel<<<8384, 256, 0, stream>>>(x, Wq, Wk, Wv, xb, Wb);
  linear_kernel<<<dim3(128, 3), 512, 0, stream>>>(xb, Wb, bq, bk, bv, q_lin, k_lin, vT);
  softmax_q_kernel<<<16384, 256, 0, stream>>>(q_lin, qb);
  softmax_k_part_kernel<<<dim3(8, 8, 16), 256, 0, stream>>>(k_lin, partials);
  softmax_k_norm_kernel<<<dim3(8, 8, 16), 256, 0, stream>>>(k_lin, partials, kb, kT);
  attn_kernel<<<dim3(8, 8, 8), 512, 0, stream>>>(qb, kb, attn);
  ctx_kernel<<<dim3(2, 2, 32), 512, 0, stream>>>(vT, kT, ctx_part);
  ctx_reduce_kernel<<<2048, 256, 0, stream>>>(ctx_part, ctxT);
  out_kernel<<<dim3(8, 4, 8), 512, 0, stream>>>(qb, ctxT, out);
}

// Round 6
// 467.309 us; speedup vs baseline: 1.0444x; 1.0444x over previous
//
#include <hip/hip_runtime.h>

typedef unsigned short u16;
typedef short bf16x8 __attribute__((ext_vector_type(8)));
typedef float f32x4 __attribute__((ext_vector_type(4)));

__device__ __forceinline__ u16 f2bf(float f) {
  union { float f; unsigned u; } v; v.f = f;
  unsigned r = v.u + 0x7fffu + ((v.u >> 16) & 1u);
  return (u16)(r >> 16);
}

#define MFMA_B16(a, b, c) __builtin_amdgcn_mfma_f32_16x16x32_bf16((a), (b), (c), 0, 0, 0)

// Stage ROWS x 64-u16 tile global->LDS, 512-thread block (8 waves).
// LDS holds swizzled layout LDS[row][slot] = global[row][slot ^ (row&7)]
// via pre-swizzled per-lane global source + linear LDS dest (rule 21/m173).
template<int ROWS>
__device__ __forceinline__ void stage8(const u16* __restrict__ gbase, int ldg,
                                       u16* lds, int tid) {
  const int wave = tid >> 6, lane = tid & 63;
  const int r8 = lane >> 3, slot = lane & 7;
#pragma unroll
  for (int j = 0; j < ROWS / 64; ++j) {
    const int chunk = wave + j * 8;
    const int row = chunk * 8 + r8;
    const u16* g = gbase + (size_t)row * ldg + ((slot ^ (row & 7)) << 3);
    __builtin_amdgcn_global_load_lds(
        (const __attribute__((address_space(1))) void*)g,
        (__attribute__((address_space(3))) void*)(lds + chunk * 512),
        16, 0, 0);
  }
}

// 256xBN tile GEMM core, 8 waves as 2(M)x4(N), wave tile 128 x BN/4.
template<int BN, int FN>
__device__ __forceinline__ void gemm_core(const u16* __restrict__ A,
                                          const u16* __restrict__ B,
                                          int ldg, int kBeg, int kEnd,
                                          u16* As, u16* Bs,
                                          f32x4 (&acc)[8][FN], int tid) {
  const int wave = tid >> 6, lane = tid & 63;
  const int wm = wave >> 2, wn = wave & 3;
  const int lrow = lane & 15, lk = lane >> 4;
  for (int k0 = kBeg; k0 < kEnd; k0 += 64) {
    __syncthreads();
    stage8<256>(A + k0, ldg, As, tid);
    stage8<BN>(B + k0, ldg, Bs, tid);
    __syncthreads();
#pragma unroll
    for (int ks = 0; ks < 2; ++ks) {
      bf16x8 b[FN];
#pragma unroll
      for (int fn = 0; fn < FN; ++fn) {
        int r = wn * (BN / 4) + fn * 16 + lrow;
        b[fn] = *(const bf16x8*)(Bs + r * 64 + (((ks * 4 + lk) ^ (r & 7)) * 8));
      }
#pragma unroll
      for (int fm = 0; fm < 8; ++fm) {
        int r = wm * 128 + fm * 16 + lrow;
        bf16x8 a = *(const bf16x8*)(As + r * 64 + (((ks * 4 + lk) ^ (r & 7)) * 8));
#pragma unroll
        for (int fn = 0; fn < FN; ++fn)
          acc[fm][fn] = MFMA_B16(a, b[fn], acc[fm][fn]);
      }
    }
  }
}

// ---------------- K0: fp32 -> bf16 conversion (x and the 3 weights) ----------------
__global__ void __launch_bounds__(256) convert_kernel(
    const float* __restrict__ x, const float* __restrict__ Wq,
    const float* __restrict__ Wk, const float* __restrict__ Wv,
    u16* __restrict__ xb, u16* __restrict__ Wb) {
  int i = blockIdx.x * 256 + threadIdx.x;
  const int NX4 = 2097152;
  if (i < NX4) {
    const float4 v = ((const float4*)x)[i];
    ushort4 o; o.x = f2bf(v.x); o.y = f2bf(v.y); o.z = f2bf(v.z); o.w = f2bf(v.w);
    ((ushort4*)xb)[i] = o;
  } else {
    int j4 = i - NX4;
    int j = j4 * 4;
    const float* W = (j < 65536) ? Wq : ((j < 131072) ? Wk : Wv);
    const float4 v = *(const float4*)(W + (j & 65535));
    ushort4 o; o.x = f2bf(v.x); o.y = f2bf(v.y); o.z = f2bf(v.z); o.w = f2bf(v.w);
    ((ushort4*)Wb)[j4] = o;
  }
}

// ---------------- K1: linear (x @ W.T + b), 256x256 tiles, permute epilogue ----------------
// v now goes to v_lin (same coalesced permuted layout as q/k, bf16) — NO 4KB scatter.
__global__ void __launch_bounds__(512) linear_kernel(
    const u16* __restrict__ xb, const u16* __restrict__ Wb,
    const float* __restrict__ bq, const float* __restrict__ bk, const float* __restrict__ bv,
    float* __restrict__ q_lin, float* __restrict__ k_lin, u16* __restrict__ v_lin) {
  __shared__ __align__(16) u16 As[256 * 64];
  __shared__ __align__(16) u16 Bs[256 * 64];
  const int tid = threadIdx.x;
  const int m0 = blockIdx.x * 256, n0 = blockIdx.y * 256;
  const int wave = tid >> 6, lane = tid & 63;
  const int wm = wave >> 2, wn = wave & 3;
  const int lrow = lane & 15, lk = lane >> 4;
  const f32x4 fzero = {0.f, 0.f, 0.f, 0.f};
  f32x4 acc[8][4];
  for (int a = 0; a < 8; ++a) for (int b = 0; b < 4; ++b) acc[a][b] = fzero;

  gemm_core<256, 4>(xb + (size_t)m0 * 256, Wb + (size_t)n0 * 256, 256, 0, 256,
                    As, Bs, acc, tid);

  const int w = n0 >> 8;  // whole tile is one of q/k/v
  for (int fm = 0; fm < 8; ++fm)
    for (int fn = 0; fn < 4; ++fn)
      for (int r = 0; r < 4; ++r) {
        int grow = wm * 128 + fm * 16 + lk * 4 + r;
        int gcol = wn * 64 + fn * 16 + lrow;
        int m = m0 + grow, j = n0 + gcol;
        int rx = m >> 11, c = m & 2047;
        int jj = j & 255, h = jj >> 5, e = jj & 31;
        int h2 = c >> 8, c2 = ((c & 255) << 3) + h, d2 = (rx << 5) + e;
        float bias = (w == 0) ? bq[jj] : ((w == 1) ? bk[jj] : bv[jj]);
        float val = acc[fm][fn][r] + bias;
        size_t qk_off = ((size_t)((h2 << 11) + c2) << 9) + d2;
        if (w == 0)      q_lin[qk_off] = val;
        else if (w == 1) k_lin[qk_off] = val;
        else             v_lin[qk_off] = f2bf(val);
      }
}

// ---------------- K1b: v_lin[h][n][d] -> vT[h][d][n] via LDS transpose ----------------
// Mirrors softmax_k_norm's proven transpose machinery.
__global__ void __launch_bounds__(256) vT_transpose_kernel(
    const u16* __restrict__ v_lin, u16* __restrict__ vT) {
  __shared__ __align__(16) u16 Ts[64 * 128];
  const int tid = threadIdx.x;
  const int dl = tid & 63, ng = tid >> 6;
  const int dt = blockIdx.x, h = blockIdx.y, nch = blockIdx.z;
  const int d0 = dt * 64, n0 = nch * 128;
  const u16* src = v_lin + ((size_t)h << 20) + ((size_t)(n0 + ng * 32) << 9) + d0 + dl;
  bf16x8 pk[4];
  #pragma unroll
  for (int i = 0; i < 32; ++i)
    pk[i >> 3][i & 7] = (short)src[(size_t)i << 9];   // coalesced across 64 lanes
  #pragma unroll
  for (int j = 0; j < 4; ++j) {
    int nl8 = ng * 4 + j;
    *(bf16x8*)(Ts + dl * 128 + (((nl8 * 8) ^ ((dl & 7) << 3)))) = pk[j];
  }
  __syncthreads();
  const int rd = tid >> 2;
  u16* vTp = vT + ((size_t)h << 20) + ((size_t)(d0 + rd) << 11) + n0;
  #pragma unroll
  for (int j = 0; j < 4; ++j) {
    int g = (tid & 3) + j * 4;
    bf16x8 vv = *(const bf16x8*)(Ts + rd * 128 + (((g * 8) ^ ((rd & 7) << 3))));
    *(bf16x8*)(vTp + g * 8) = vv;
  }
}

// ---------------- K2: softmax over d (512) per (h,n) row; fold *sqrt(512) ----------------
__global__ void __launch_bounds__(256) softmax_q_kernel(
    const float* __restrict__ q_lin, u16* __restrict__ qb) {
  const int row = blockIdx.x, tid = threadIdx.x;
  const int wave = tid >> 6, lane = tid & 63;
  const float* src = q_lin + ((size_t)row << 9);
  float v0 = src[tid], v1 = src[tid + 256];
  float m = fmaxf(v0, v1);
  for (int o = 32; o; o >>= 1) m = fmaxf(m, __shfl_xor(m, o));
  __shared__ float red[8];
  if (lane == 0) red[wave] = m;
  __syncthreads();
  m = fmaxf(fmaxf(red[0], red[1]), fmaxf(red[2], red[3]));
  float e0 = expf(v0 - m), e1 = expf(v1 - m);
  float s = e0 + e1;
  for (int o = 32; o; o >>= 1) s += __shfl_xor(s, o);
  if (lane == 0) red[4 + wave] = s;
  __syncthreads();
  s = red[4] + red[5] + red[6] + red[7];
  float sc = 22.627416997969522f / s;
  u16* dst = qb + ((size_t)row << 9);
  dst[tid] = f2bf(e0 * sc);
  dst[tid + 256] = f2bf(e1 * sc);
}

// ---------------- K3a: per-chunk partial (max, sum-exp) over n for each (h,d) column ----------------
__global__ void __launch_bounds__(256) softmax_k_part_kernel(
    const float* __restrict__ k_lin, float2* __restrict__ partials) {
  const int tid = threadIdx.x;
  const int dl = tid & 63, ng = tid >> 6;
  const int dt = blockIdx.x, h = blockIdx.y, nch = blockIdx.z;
  const int d = dt * 64 + dl;
  const float* base = k_lin + ((size_t)h << 20) + ((size_t)(nch * 128 + ng * 32) << 9) + d;
  float v[32];
  #pragma unroll
  for (int i = 0; i < 32; ++i) v[i] = base[(size_t)i << 9];
  float m = v[0];
  #pragma unroll
  for (int i = 1; i < 32; ++i) m = fmaxf(m, v[i]);
  __shared__ float2 red[4][64];
  red[ng][dl].x = m;
  __syncthreads();
  float M = fmaxf(fmaxf(red[0][dl].x, red[1][dl].x), fmaxf(red[2][dl].x, red[3][dl].x));
  float s = 0.f;
  #pragma unroll
  for (int i = 0; i < 32; ++i) s += __expf(v[i] - M);
  red[ng][dl].y = s;
  __syncthreads();
  if (ng == 0) {
    float S = red[0][dl].y + red[1][dl].y + red[2][dl].y + red[3][dl].y;
    partials[(((h * 8 + dt) * 16 + nch) << 6) + dl] = make_float2(M, S);
  }
}

// ---------------- K3c: combine partials, normalize, write kb (coalesced) + kT (LDS transpose) ----------------
__global__ void __launch_bounds__(256) softmax_k_norm_kernel(
    const float* __restrict__ k_lin, const float2* __restrict__ partials,
    u16* __restrict__ kb, u16* __restrict__ kT) {
  __shared__ __align__(16) u16 Ts[64 * 128];
  const int tid = threadIdx.x;
  const int dl = tid & 63, ng = tid >> 6;
  const int dt = blockIdx.x, h = blockIdx.y, nch = blockIdx.z;
  const int d0 = dt * 64, n0 = nch * 128;
  const float2* pb = partials + (((h * 8 + dt) * 16) << 6) + dl;
  float2 pj[16];
  float M = -3.0e38f;
  #pragma unroll
  for (int j = 0; j < 16; ++j) { pj[j] = pb[j << 6]; M = fmaxf(M, pj[j].x); }
  float S = 0.f;
  #pragma unroll
  for (int j = 0; j < 16; ++j) S += pj[j].y * __expf(pj[j].x - M);
  float inv = 1.0f / S;
  const float* src = k_lin + ((size_t)h << 20) + ((size_t)(n0 + ng * 32) << 9) + d0 + dl;
  u16* kbp = kb + ((size_t)h << 20) + ((size_t)(n0 + ng * 32) << 9) + d0 + dl;
  bf16x8 pk[4];
  #pragma unroll
  for (int i = 0; i < 32; ++i) {
    float e = __expf(src[(size_t)i << 9] - M) * inv;
    u16 b = f2bf(e);
    kbp[(size_t)i << 9] = b;
    pk[i >> 3][i & 7] = (short)b;
  }
  #pragma unroll
  for (int j = 0; j < 4; ++j) {
    int nl8 = ng * 4 + j;
    *(bf16x8*)(Ts + dl * 128 + (((nl8 * 8) ^ ((dl & 7) << 3)))) = pk[j];
  }
  __syncthreads();
  const int rd = tid >> 2;
  u16* kTp = kT + ((size_t)h << 20) + ((size_t)(d0 + rd) << 11) + n0;
  #pragma unroll
  for (int j = 0; j < 4; ++j) {
    int g = (tid & 3) + j * 4;
    bf16x8 vv = *(const bf16x8*)(Ts + rd * 128 + (((g * 8) ^ ((rd & 7) << 3))));
    *(bf16x8*)(kTp + g * 8) = vv;
  }
}

// ---------------- K4: attn[h,n,m] = sum_d qb[h,n,d]*kb[h,m,d]  (NT, 256x256, K=512) ----------------
__global__ void __launch_bounds__(512) attn_kernel(
    const u16* __restrict__ qb, const u16* __restrict__ kb, float* __restrict__ attn) {
  __shared__ __align__(16) u16 As[256 * 64];
  __shared__ __align__(16) u16 Bs[256 * 64];
  const int tid = threadIdx.x, h = blockIdx.z;
  const int n0 = blockIdx.x * 256, mm0 = blockIdx.y * 256;
  const int wave = tid >> 6, lane = tid & 63;
  const int wm = wave >> 2, wn = wave & 3;
  const int lrow = lane & 15, lk = lane >> 4;
  const f32x4 fzero = {0.f, 0.f, 0.f, 0.f};
  f32x4 acc[8][4];
  for (int a = 0; a < 8; ++a) for (int b = 0; b < 4; ++b) acc[a][b] = fzero;

  gemm_core<256, 4>(qb + ((size_t)h << 20) + (size_t)n0 * 512,
                    kb + ((size_t)h << 20) + (size_t)mm0 * 512,
                    512, 0, 512, As, Bs, acc, tid);

  float* dst = attn + ((size_t)h << 22);
  for (int fm = 0; fm < 8; ++fm)
    for (int fn = 0; fn < 4; ++fn)
      for (int r = 0; r < 4; ++r) {
        int row = n0 + wm * 128 + fm * 16 + lk * 4 + r;
        int col = mm0 + wn * 64 + fn * 16 + lrow;
        dst[((size_t)row << 11) + col] = acc[fm][fn][r];
      }
}

// ---------------- K5: ctx partials (split-K=4): part[s][h][e][d] = sum_{n in slice} vT*kT ----------------
__global__ void __launch_bounds__(512) ctx_kernel(
    const u16* __restrict__ vT, const u16* __restrict__ kT, float* __restrict__ part) {
  __shared__ __align__(16) u16 As[256 * 64];
  __shared__ __align__(16) u16 Bs[256 * 64];
  const int tid = threadIdx.x;
  const int h = blockIdx.z >> 2, s = blockIdx.z & 3;
  const int e0 = blockIdx.x * 256, d0 = blockIdx.y * 256;
  const int wave = tid >> 6, lane = tid & 63;
  const int wm = wave >> 2, wn = wave & 3;
  const int lrow = lane & 15, lk = lane >> 4;
  const f32x4 fzero = {0.f, 0.f, 0.f, 0.f};
  f32x4 acc[8][4];
  for (int a = 0; a < 8; ++a) for (int b = 0; b < 4; ++b) acc[a][b] = fzero;

  gemm_core<256, 4>(vT + ((size_t)h << 20) + (size_t)e0 * 2048,
                    kT + ((size_t)h << 20) + (size_t)d0 * 2048,
                    2048, s * 512, s * 512 + 512, As, Bs, acc, tid);

  float* dst = part + ((size_t)(s * 8 + h) << 18);
  for (int fm = 0; fm < 8; ++fm)
    for (int fn = 0; fn < 4; ++fn)
      for (int r = 0; r < 4; ++r) {
        int erow = e0 + wm * 128 + fm * 16 + lk * 4 + r;
        int dcol = d0 + wn * 64 + fn * 16 + lrow;
        dst[((size_t)erow << 9) + dcol] = acc[fm][fn][r];
      }
}

// ---------------- K5b: reduce the 4 split-K partials -> ctxT bf16 ----------------
__global__ void __launch_bounds__(256) ctx_reduce_kernel(
    const float* __restrict__ part, u16* __restrict__ ctxT) {
  int i = blockIdx.x * 256 + threadIdx.x;       // float4 index, 524288 total
  const float4* p = (const float4*)part;
  float4 s0 = p[i], s1 = p[i + (1 << 19)], s2 = p[i + (2 << 19)], s3 = p[i + 3 * (1 << 19)];
  ushort4 o;
  o.x = f2bf(s0.x + s1.x + s2.x + s3.x);
  o.y = f2bf(s0.y + s1.y + s2.y + s3.y);
  o.z = f2bf(s0.z + s1.z + s2.z + s3.z);
  o.w = f2bf(s0.w + s1.w + s2.w + s3.w);
  ((ushort4*)ctxT)[i] = o;
}

// ---------------- K6: out[h,n,e] = sum_d qb*ctxT (NT, 256x128, K=512) + inverse permute ----------------
__global__ void __launch_bounds__(512) out_kernel(
    const u16* __restrict__ qb, const u16* __restrict__ ctxT, float* __restrict__ out) {
  __shared__ __align__(16) u16 As[256 * 64];
  __shared__ __align__(16) u16 Bs[128 * 64];
  const int tid = threadIdx.x, h = blockIdx.z;
  const int n0 = blockIdx.x * 256, e0 = blockIdx.y * 128;
  const int wave = tid >> 6, lane = tid & 63;
  const int wm = wave >> 2, wn = wave & 3;
  const int lrow = lane & 15, lk = lane >> 4;
  const f32x4 fzero = {0.f, 0.f, 0.f, 0.f};
  f32x4 acc[8][2];
  for (int a = 0; a < 8; ++a) for (int b = 0; b < 2; ++b) acc[a][b] = fzero;

  gemm_core<128, 2>(qb + ((size_t)h << 20) + (size_t)n0 * 512,
                    ctxT + ((size_t)h << 18) + (size_t)e0 * 512,
                    512, 0, 512, As, Bs, acc, tid);

  for (int fm = 0; fm < 8; ++fm)
    for (int fn = 0; fn < 2; ++fn)
      for (int r = 0; r < 4; ++r) {
        int n = n0 + wm * 128 + fm * 16 + lk * 4 + r;
        int e = e0 + wn * 32 + fn * 16 + lrow;
        size_t dstIdx = ((size_t)(((e >> 5) << 11) + n) << 8) + (h << 5) + (e & 31);
        out[dstIdx] = acc[fm][fn][r];
      }
}

extern "C" void kernel_launch(void* const* d_in, const int* in_sizes, int n_in,
                              void* d_out, int out_size, void* d_ws, size_t ws_size,
                              hipStream_t stream) {
  const float* x  = (const float*)d_in[0];
  const float* Wq = (const float*)d_in[1];
  const float* bq = (const float*)d_in[2];
  const float* Wk = (const float*)d_in[3];
  const float* bk = (const float*)d_in[4];
  const float* Wv = (const float*)d_in[5];
  const float* bv = (const float*)d_in[6];
  float* out  = (float*)d_out;
  float* attn = out + 8388608;

  char* ws = (char*)d_ws;
  u16*   xb    = (u16*)(ws);                      // 16,777,216 B
  u16*   Wb    = (u16*)(ws + 16777216);           //    393,216 B
  float* q_lin = (float*)(ws + 17170432);         // 33,554,432 B
  float* k_lin = (float*)(ws + 50724864);         // 33,554,432 B
  u16*   v_lin = (u16*)(ws + 84279296);           // 16,777,216 B
  u16*   vT    = (u16*)(ws + 101056512);          // 16,777,216 B (ends 117,833,728)
  u16*   qb    = (u16*)(ws);                      // over xb    (dead after K1)
  u16*   kb    = (u16*)(ws + 17170432);           // over q_lin (dead after K2)
  u16*   kT    = (u16*)(ws + 33947648);
  u16*   ctxT  = (u16*)(ws + 50724864);           // over k_lin (dead after K3)
  float* ctx_part = (float*)(ws + 134217728);     // 33,554,432 B split-K partials
  float2* partials = (float2*)(attn + 33554432 - 131072);

  convert_kernel<<<8384, 256, 0, stream>>>(x, Wq, Wk, Wv, xb, Wb);
  linear_kernel<<<dim3(128, 3), 512, 0, stream>>>(xb, Wb, bq, bk, bv, q_lin, k_lin, v_lin);
  vT_transpose_kernel<<<dim3(8, 8, 16), 256, 0, stream>>>(v_lin, vT);
  softmax_q_kernel<<<16384, 256, 0, stream>>>(q_lin, qb);
  softmax_k_part_kernel<<<dim3(8, 8, 16), 256, 0, stream>>>(k_lin, partials);
  softmax_k_norm_kernel<<<dim3(8, 8, 16), 256, 0, stream>>>(k_lin, partials, kb, kT);
  attn_kernel<<<dim3(8, 8, 8), 512, 0, stream>>>(qb, kb, attn);
  ctx_kernel<<<dim3(2, 2, 32), 512, 0, stream>>>(vT, kT, ctx_part);
  ctx_reduce_kernel<<<2048, 256, 0, stream>>>(ctx_part, ctxT);
  out_kernel<<<dim3(8, 4, 8), 512, 0, stream>>>(qb, ctxT, out);
}